// Round 1
// baseline (381.048 us; speedup 1.0000x reference)
//
#include <hip/hip_runtime.h>

// BoundedMultiResGrid: 4-level dense grid trilinear interpolation.
// Inputs (setup_inputs order): x [N,3] f32, emb0 [16^3,2], emb1 [32^3,2],
// emb2 [64^3,2], emb3 [128^3,2] (all f32).
// Output (concat flat): features [N,8] f32, then mask [N] (1.0/0.0).

constexpr int NPTS = 4000000;

template <int R>
__device__ __forceinline__ float2 level_interp(const float2* __restrict__ e,
                                               float ux, float uy, float uz) {
    // ux,uy,uz already clamped to [0,1]
    const float s = (float)(R - 1);
    float sx = ux * s, sy = uy * s, sz = uz * s;
    // sx >= 0, so (int) truncation == floor
    int ix = min((int)sx, R - 2);
    int iy = min((int)sy, R - 2);
    int iz = min((int)sz, R - 2);
    float fx = sx - (float)ix;
    float fy = sy - (float)iy;
    float fz = sz - (float)iz;

    int b00 = (ix * R + iy) * R + iz;     // (ix, iy,   iz)
    int b01 = b00 + R;                    // (ix, iy+1, iz)
    int b10 = b00 + R * R;                // (ix+1, iy, iz)
    int b11 = b10 + R;                    // (ix+1, iy+1, iz)

    // z and z+1 are adjacent float2's -> contiguous 16B per corner pair
    float2 c000 = e[b00], c001 = e[b00 + 1];
    float2 c010 = e[b01], c011 = e[b01 + 1];
    float2 c100 = e[b10], c101 = e[b10 + 1];
    float2 c110 = e[b11], c111 = e[b11 + 1];

    float gz = 1.0f - fz, gy = 1.0f - fy, gx = 1.0f - fx;

    float2 c00, c01, c10, c11;
    c00.x = c000.x * gz + c001.x * fz;  c00.y = c000.y * gz + c001.y * fz;
    c01.x = c010.x * gz + c011.x * fz;  c01.y = c010.y * gz + c011.y * fz;
    c10.x = c100.x * gz + c101.x * fz;  c10.y = c100.y * gz + c101.y * fz;
    c11.x = c110.x * gz + c111.x * fz;  c11.y = c110.y * gz + c111.y * fz;

    float2 c0, c1;
    c0.x = c00.x * gy + c01.x * fy;  c0.y = c00.y * gy + c01.y * fy;
    c1.x = c10.x * gy + c11.x * fy;  c1.y = c10.y * gy + c11.y * fy;

    float2 r;
    r.x = c0.x * gx + c1.x * fx;
    r.y = c0.y * gx + c1.y * fx;
    return r;
}

__global__ __launch_bounds__(256) void grid_kernel(
    const float* __restrict__ x,
    const float2* __restrict__ e0,
    const float2* __restrict__ e1,
    const float2* __restrict__ e2,
    const float2* __restrict__ e3,
    float4* __restrict__ feat,   // [N, 8] viewed as [N*2] float4
    float* __restrict__ maskf,   // [N]
    int n)
{
    int i = blockIdx.x * blockDim.x + threadIdx.x;
    if (i >= n) return;

    float x0 = x[3 * i + 0];
    float x1 = x[3 * i + 1];
    float x2 = x[3 * i + 2];

    bool m = (x0 >= 0.0f) && (x0 <= 1.0f) &&
             (x1 >= 0.0f) && (x1 <= 1.0f) &&
             (x2 >= 0.0f) && (x2 <= 1.0f);
    float mm = m ? 1.0f : 0.0f;

    float ux = fminf(fmaxf(x0, 0.0f), 1.0f);
    float uy = fminf(fmaxf(x1, 0.0f), 1.0f);
    float uz = fminf(fmaxf(x2, 0.0f), 1.0f);

    float2 f0 = level_interp<16>(e0, ux, uy, uz);
    float2 f1 = level_interp<32>(e1, ux, uy, uz);
    float2 f2 = level_interp<64>(e2, ux, uy, uz);
    float2 f3 = level_interp<128>(e3, ux, uy, uz);

    float4 o0 = make_float4(f0.x * mm, f0.y * mm, f1.x * mm, f1.y * mm);
    float4 o1 = make_float4(f2.x * mm, f2.y * mm, f3.x * mm, f3.y * mm);

    feat[2 * i + 0] = o0;
    feat[2 * i + 1] = o1;
    maskf[i] = mm;
}

extern "C" void kernel_launch(void* const* d_in, const int* in_sizes, int n_in,
                              void* d_out, int out_size, void* d_ws, size_t ws_size,
                              hipStream_t stream) {
    const float* x = (const float*)d_in[0];
    const float2* e0 = (const float2*)d_in[1];
    const float2* e1 = (const float2*)d_in[2];
    const float2* e2 = (const float2*)d_in[3];
    const float2* e3 = (const float2*)d_in[4];

    int n = in_sizes[0] / 3;               // N points
    float* feat = (float*)d_out;           // N*8 floats
    float* maskf = feat + (size_t)n * 8;   // N floats

    int block = 256;
    int grid = (n + block - 1) / block;
    grid_kernel<<<grid, block, 0, stream>>>(x, e0, e1, e2, e3,
                                            (float4*)feat, maskf, n);
}